// Round 2
// baseline (309.201 us; speedup 1.0000x reference)
//
#include <hip/hip_runtime.h>
#include <math.h>

#define BSZ 32
#define SEQ 4096
#define ENCD 512
#define TMAX 64

__device__ __forceinline__ float dot4(float4 a, float4 b) {
    return a.x * b.x + a.y * b.y + a.z * b.z + a.w * b.w;
}

// Fused stage 1+2: one 256-thread block per batch.
// Each of the 4 waves computes L/R projections for 16 gathered rows (W held
// in registers, gather loads unrolled x4), results staged in LDS, then the
// block walks all (j,k) pairs for the masked CE sum.
__global__ __launch_bounds__(256) void fused_kernel(
    const float* __restrict__ enc, const int* __restrict__ ids,
    const int* __restrict__ tlen, const float* __restrict__ W,
    const float* __restrict__ bias, float* __restrict__ partial) {
    int b = blockIdx.x;
    int tid = threadIdx.x;
    int lane = tid & 63;
    int wv = tid >> 6;

    __shared__ int sids[TMAX];
    __shared__ float4 slr[TMAX];
    __shared__ float ssum[4], scnt[4];

    if (tid < TMAX) sids[tid] = ids[b * TMAX + tid];
    __syncthreads();

    // W is (2, 2*ENC) row-major: W[0][:512]=Wl0, W[0][512:]=Wr0,
    //                            W[1][:512]=Wl1, W[1][512:]=Wr1
    const float4* W4 = (const float4*)W;
    int l2 = lane * 2;
    float4 wl0a = W4[l2],       wl0b = W4[l2 + 1];
    float4 wr0a = W4[128 + l2], wr0b = W4[128 + l2 + 1];
    float4 wl1a = W4[256 + l2], wl1b = W4[256 + l2 + 1];
    float4 wr1a = W4[384 + l2], wr1b = W4[384 + l2 + 1];

    for (int t0 = wv * 16; t0 < wv * 16 + 16; t0 += 4) {
        float4 xa[4], xb[4];
#pragma unroll
        for (int r = 0; r < 4; r++) {
            int id = sids[t0 + r];
            const float4* x4 =
                (const float4*)(enc + ((size_t)b * SEQ + (size_t)id) * ENCD) + l2;
            xa[r] = x4[0];
            xb[r] = x4[1];
        }
#pragma unroll
        for (int r = 0; r < 4; r++) {
            float s0 = dot4(xa[r], wl0a) + dot4(xb[r], wl0b);  // left, o=0
            float s1 = dot4(xa[r], wl1a) + dot4(xb[r], wl1b);  // left, o=1
            float s2 = dot4(xa[r], wr0a) + dot4(xb[r], wr0b);  // right, o=0
            float s3 = dot4(xa[r], wr1a) + dot4(xb[r], wr1b);  // right, o=1
#pragma unroll
            for (int off = 32; off; off >>= 1) {
                s0 += __shfl_down(s0, off);
                s1 += __shfl_down(s1, off);
                s2 += __shfl_down(s2, off);
                s3 += __shfl_down(s3, off);
            }
            if (lane == 0) slr[t0 + r] = make_float4(s0, s1, s2, s3);
        }
    }
    __syncthreads();

    int T = tlen[b];
    float b0 = bias[0], b1 = bias[1];
    float sum = 0.f, cnt = 0.f;
    for (int idx = tid; idx < TMAX * TMAX; idx += 256) {
        int j = idx >> 6, k = idx & 63;
        if (k < j && j < T) {
            float4 Lj = slr[j];
            float4 Rk = slr[k];
            float l0 = Lj.x + Rk.z + b0;
            float l1 = Lj.y + Rk.w + b1;
            float m = fmaxf(l0, l1);
            float lse = m + logf(expf(l0 - m) + expf(l1 - m));
            float lp = (k == j - 1) ? (l1 - lse) : (l0 - lse);
            sum -= lp;
            cnt += 1.f;
        }
    }
#pragma unroll
    for (int off = 32; off; off >>= 1) {
        sum += __shfl_down(sum, off);
        cnt += __shfl_down(cnt, off);
    }
    if (lane == 0) { ssum[wv] = sum; scnt[wv] = cnt; }
    __syncthreads();
    if (tid == 0) {
        float S = ssum[0] + ssum[1] + ssum[2] + ssum[3];
        float C = scnt[0] + scnt[1] + scnt[2] + scnt[3];
        partial[b * 2] = S;
        partial[b * 2 + 1] = C;
    }
}

// Final: reduce 32 per-batch partials -> scalar loss.
__global__ __launch_bounds__(64) void final_kernel(
    const float* __restrict__ partial, float* __restrict__ out) {
    int lane = threadIdx.x;
    float s = 0.f, c = 0.f;
    if (lane < BSZ) { s = partial[lane * 2]; c = partial[lane * 2 + 1]; }
#pragma unroll
    for (int off = 32; off; off >>= 1) {
        s += __shfl_down(s, off);
        c += __shfl_down(c, off);
    }
    if (lane == 0) out[0] = s / fmaxf(c, 1.f);
}

extern "C" void kernel_launch(void* const* d_in, const int* in_sizes, int n_in,
                              void* d_out, int out_size, void* d_ws, size_t ws_size,
                              hipStream_t stream) {
    const float* enc  = (const float*)d_in[0];   // (32, 4096, 512) f32
    const int*   ids  = (const int*)d_in[1];     // (32, 64) i32
    const int*   tlen = (const int*)d_in[2];     // (32,) i32
    const float* W    = (const float*)d_in[3];   // (2, 1024) f32
    const float* bias = (const float*)d_in[4];   // (2,) f32
    float* out = (float*)d_out;

    float* partial = (float*)d_ws;               // 64 floats

    fused_kernel<<<BSZ, 256, 0, stream>>>(enc, ids, tlen, W, bias, partial);
    final_kernel<<<1, 64, 0, stream>>>(partial, out);
}